// Round 8
// baseline (779.970 us; speedup 1.0000x reference)
//
#include <hip/hip_runtime.h>
#include <hip/hip_bf16.h>
#include <math.h>

// Problem constants
#define BB 32
#define TT 12
#define NN 512
#define HH 64
#define DIN 65
#define MSUB 96        // ROWS/16 (ROWS = 3*512)
#define RTOT 16384     // BB*NN dense rows
#define PSUB 5         // 80 padded cols per batch

typedef _Float16 f16;
typedef f16 f16x8 __attribute__((ext_vector_type(8)));
typedef float f32x4 __attribute__((ext_vector_type(4)));

// Bf element address: node j (K-dim), batch b, local col p in [0,80)
__device__ __forceinline__ size_t bf_addr(int j, int b, int p) {
    return ((size_t)(((j >> 5) * 32 + b) * PSUB + (p >> 4)) * 64 + ((j >> 3) & 3) * 16 + (p & 15)) * 8 + (j & 7);
}

// ---------------- convert P (f32, 1536x512 row-major) -> fragment-major f16 A ----------------
__global__ __launch_bounds__(256) void conv_a(const float* __restrict__ P, f16* __restrict__ Af) {
    int u = blockIdx.x * 256 + threadIdx.x;  // 1536*512/8 slots
    int lane = u & 63;
    int su = u >> 6;
    int ks = su / MSUB, ms = su - ks * MSUB;
    int m = ms * 16 + (lane & 15);
    int k = ks * 32 + (lane >> 4) * 8;
    const float* src = &P[(size_t)m * 512 + k];
    f16x8 v;
#pragma unroll
    for (int i = 0; i < 8; ++i) v[i] = (f16)src[i];
    *(f16x8*)&Af[(size_t)u * 8] = v;
}

// -------- convert dense weight (195 x O f32) -> K-permuted fragment pack matching in-reg S^T --
// slot = s*OS + os; lane (o_l,g); elem i: f = 2s + (i>=4), (kl,ps) = f/5,f%5,
// p = ps*16 + 4g + (i&3), k_orig = kl*65 + p; zero if f==15 or p>=65.
__global__ __launch_bounds__(256) void conv_w(const float* __restrict__ W, int O, int OS,
                                              f16* __restrict__ Wf) {
    int u = blockIdx.x * 256 + threadIdx.x;
    if (u >= 8 * OS * 64) return;
    int lane = u & 63, slot = u >> 6;
    int s = slot / OS, os = slot - s * OS;
    int o = os * 16 + (lane & 15);
    int g = lane >> 4;
    f16x8 v;
#pragma unroll
    for (int i = 0; i < 8; ++i) {
        int f = 2 * s + (i >= 4 ? 1 : 0);
        int kl = f / 5, ps = f - kl * 5;
        int p = ps * 16 + 4 * g + (i & 3);
        v[i] = (f < 15 && p < 65) ? (f16)W[(size_t)(kl * 65 + p) * O + o] : (f16)0.f;
    }
    *(f16x8*)&Wf[(size_t)u * 8] = v;
}

// ---------------- write x[b,t,:,0] into Bf p=0 col (prologue) ----------------
__global__ __launch_bounds__(256) void upd_x(const float* __restrict__ x, int t,
                                             f16* __restrict__ Bf) {
    int idx = blockIdx.x * 256 + threadIdx.x;
    if (idx >= RTOT) return;
    int b = idx >> 9, n = idx & 511;
    Bf[bf_addr(n, b, 0)] = (f16)x[((size_t)b * TT + t) * NN + n];
}

// ---------------- mm: S^T chunk for (batch b, node-band mb) into acc[15], all reg-direct ------
// acc[f=kl*5+ps] at lane (node_l=lane&15, g): S[kl*512+node][b, p=ps*16+4g+rI]
// No LDS, no barriers: operands are L2-resident in fragment-major order; coalesced 16B/lane.
__device__ __forceinline__ void gcn_mm(const f16* __restrict__ Af,
                                       const f16* __restrict__ BfIn,
                                       int b, int mb, int wave, int lane,
                                       f32x4 (&acc)[15]) {
#pragma unroll
    for (int ks = 0; ks < 16; ++ks) {
        f16x8 bfr[5], afr[3];
#pragma unroll
        for (int ps = 0; ps < PSUB; ++ps)
            bfr[ps] = *(const f16x8*)&BfIn[((size_t)((ks * 32 + b) * PSUB + ps) * 64 + lane) * 8];
#pragma unroll
        for (int k = 0; k < 3; ++k) {
            int msub = k * 32 + mb * 4 + wave;
            afr[k] = *(const f16x8*)&Af[((size_t)(ks * MSUB + msub) * 64 + lane) * 8];
        }
#pragma unroll
        for (int k = 0; k < 3; ++k)
#pragma unroll
            for (int ps = 0; ps < PSUB; ++ps)
                acc[k * 5 + ps] = __builtin_amdgcn_mfma_f32_16x16x32_f16(bfr[ps], afr[k], acc[k * 5 + ps], 0, 0, 0);
    }
}

// build dense A-operand fragments from acc (K-permuted to match conv_w)
__device__ __forceinline__ void build_ad(const f32x4 (&acc)[15], f16x8 (&ad)[8]) {
#pragma unroll
    for (int s = 0; s < 8; ++s)
#pragma unroll
        for (int i = 0; i < 4; ++i) {
            ad[s][i] = (f16)acc[2 * s][i];
            ad[s][4 + i] = (s < 7) ? (f16)acc[2 * s + 1][i] : (f16)0.f;
        }
}

// ---------------- fused gates phase: mm + zr-dense + sigmoid; z->zf, r*h->BfOut; p0 copy ------
__global__ __launch_bounds__(256) void fused_gates(const f16* __restrict__ Af,
                                                   const f16* __restrict__ BfIn,
                                                   f16* __restrict__ BfOut,
                                                   const f16* __restrict__ Wf,
                                                   const float* __restrict__ bias,
                                                   const float* __restrict__ hf,
                                                   float* __restrict__ zf) {
    int tid = threadIdx.x, wave = tid >> 6, lane = tid & 63;
    int b = blockIdx.x >> 3, mb = blockIdx.x & 7;
    f32x4 acc[15] = {};
    gcn_mm(Af, BfIn, b, mb, wave, lane, acc);

    f16x8 ad[8];
    build_ad(acc, ad);

    f32x4 acc2[8] = {};
#pragma unroll
    for (int s = 0; s < 8; ++s)
#pragma unroll
        for (int os = 0; os < 8; ++os) {
            f16x8 w = *(const f16x8*)&Wf[((size_t)(s * 8 + os) * 64 + lane) * 8];
            acc2[os] = __builtin_amdgcn_mfma_f32_16x16x32_f16(ad[s], w, acc2[os], 0, 0, 0);
        }

    int o_l = lane & 15, g = lane >> 4;
    int node0 = mb * 64 + wave * 16;
    int rf = b * 32 + mb * 4 + wave;
#pragma unroll
    for (int os = 0; os < 4; ++os) {  // z
        f32x4 v;
#pragma unroll
        for (int rI = 0; rI < 4; ++rI)
            v[rI] = 1.f / (1.f + expf(-(acc2[os][rI] + bias[os * 16 + o_l])));
        *(f32x4*)&zf[((size_t)(rf * 4 + os) * 64 + lane) * 4] = v;
    }
#pragma unroll
    for (int os = 4; os < 8; ++os) {  // r -> r*h
        int osh = os - 4;
        f32x4 hv = *(const f32x4*)&hf[((size_t)(rf * 4 + osh) * 64 + lane) * 4];
#pragma unroll
        for (int rI = 0; rI < 4; ++rI) {
            float rr = 1.f / (1.f + expf(-(acc2[os][rI] + bias[64 + osh * 16 + o_l])));
            int n = node0 + 4 * g + rI;
            BfOut[bf_addr(n, b, 1 + osh * 16 + o_l)] = (f16)(rr * hv[rI]);
        }
    }
    if (tid < 64) {  // p0 col copy (x or go)
        int n = mb * 64 + tid;
        BfOut[bf_addr(n, b, 0)] = BfIn[bf_addr(n, b, 0)];
    }
}

// -------- fused cand phase: mm + cand-dense + tanh + GRU update; h->hf,BfOut; tail x/proj -----
__global__ __launch_bounds__(256) void fused_cand(const f16* __restrict__ Af,
                                                  const f16* __restrict__ BfIn,
                                                  f16* __restrict__ BfOut,
                                                  const f16* __restrict__ Wf,
                                                  const float* __restrict__ bias,
                                                  const float* __restrict__ zf,
                                                  float* __restrict__ hf,
                                                  const float* __restrict__ xnext, int tnext,
                                                  const float* __restrict__ Wp,
                                                  const float* __restrict__ bp,
                                                  float* __restrict__ outp, int t, int hor,
                                                  int mode) {
    int tid = threadIdx.x, wave = tid >> 6, lane = tid & 63;
    int b = blockIdx.x >> 3, mb = blockIdx.x & 7;
    f32x4 acc[15] = {};
    gcn_mm(Af, BfIn, b, mb, wave, lane, acc);

    f16x8 ad[8];
    build_ad(acc, ad);

    f32x4 acc2[4] = {};
#pragma unroll
    for (int s = 0; s < 8; ++s)
#pragma unroll
        for (int os = 0; os < 4; ++os) {
            f16x8 w = *(const f16x8*)&Wf[((size_t)(s * 4 + os) * 64 + lane) * 8];
            acc2[os] = __builtin_amdgcn_mfma_f32_16x16x32_f16(ad[s], w, acc2[os], 0, 0, 0);
        }

    int o_l = lane & 15, g = lane >> 4;
    int node0 = mb * 64 + wave * 16;
    int rf = b * 32 + mb * 4 + wave;
    float pp[4] = {0.f, 0.f, 0.f, 0.f};
#pragma unroll
    for (int os = 0; os < 4; ++os) {
        int o = os * 16 + o_l;
        float wp = mode ? Wp[o] : 0.f;
        f32x4 zv = *(const f32x4*)&zf[((size_t)(rf * 4 + os) * 64 + lane) * 4];
        f32x4 hv = *(const f32x4*)&hf[((size_t)(rf * 4 + os) * 64 + lane) * 4];
        f32x4 hn;
#pragma unroll
        for (int rI = 0; rI < 4; ++rI) {
            float hc = tanhf(acc2[os][rI] + bias[o]);
            hn[rI] = (1.f - zv[rI]) * hv[rI] + zv[rI] * hc;
            pp[rI] += hn[rI] * wp;
        }
        *(f32x4*)&hf[((size_t)(rf * 4 + os) * 64 + lane) * 4] = hn;
#pragma unroll
        for (int rI = 0; rI < 4; ++rI) {
            int n = node0 + 4 * g + rI;
            BfOut[bf_addr(n, b, 1 + o)] = (f16)hn[rI];
        }
    }
    if (mode) {  // decoder: proj + out + p0
#pragma unroll
        for (int m = 1; m < 16; m <<= 1)
#pragma unroll
            for (int rI = 0; rI < 4; ++rI) pp[rI] += __shfl_xor(pp[rI], m, 64);
        if (o_l == 0) {
#pragma unroll
            for (int rI = 0; rI < 4; ++rI) {
                int n = node0 + 4 * g + rI;
                float v = pp[rI] + bp[0];
                outp[((size_t)b * hor + t) * NN + n] = v;
                BfOut[bf_addr(n, b, 0)] = (f16)v;
            }
        }
    } else {  // encoder: next x (or 0 at seam)
        if (o_l == 0) {
#pragma unroll
            for (int rI = 0; rI < 4; ++rI) {
                int n = node0 + 4 * g + rI;
                float v = xnext ? xnext[((size_t)b * TT + tnext) * NN + n] : 0.f;
                BfOut[bf_addr(n, b, 0)] = (f16)v;
            }
        }
    }
}

extern "C" void kernel_launch(void* const* d_in, const int* in_sizes, int n_in,
                              void* d_out, int out_size, void* d_ws, size_t ws_size,
                              hipStream_t stream) {
    const float* x   = (const float*)d_in[0];
    const float* P   = (const float*)d_in[1];
    const float* Weg = (const float*)d_in[2];
    const float* beg = (const float*)d_in[3];
    const float* Weu = (const float*)d_in[4];
    const float* beu = (const float*)d_in[5];
    const float* Wdg = (const float*)d_in[6];
    const float* bdg = (const float*)d_in[7];
    const float* Wdu = (const float*)d_in[8];
    const float* bdu = (const float*)d_in[9];
    const float* Wp  = (const float*)d_in[10];
    const float* bp  = (const float*)d_in[11];
    float* out = (float*)d_out;
    int hor = out_size / (BB * NN);

    float* ws = (float*)d_ws;
    size_t off = 0;
    float* hf = ws + off; off += (size_t)RTOT * HH;                    // 4 MB
    float* zf = ws + off; off += (size_t)RTOT * HH;                    // 4 MB
    f16* BfA  = (f16*)(ws + off); off += 16 * 32 * PSUB * 64 * 8 / 2;  // 2.62 MB
    f16* BfB  = (f16*)(ws + off); off += 16 * 32 * PSUB * 64 * 8 / 2;
    f16* Af   = (f16*)(ws + off); off += (size_t)MSUB * 16 * 512 / 2;
    f16* WfGe = (f16*)(ws + off); off += 8 * 8 * 64 * 8 / 2;
    f16* WfGd = (f16*)(ws + off); off += 8 * 8 * 64 * 8 / 2;
    f16* WfCe = (f16*)(ws + off); off += 8 * 4 * 64 * 8 / 2;
    f16* WfCd = (f16*)(ws + off); off += 8 * 4 * 64 * 8 / 2;

    size_t bf_bytes = (size_t)16 * 32 * PSUB * 64 * 8 * sizeof(f16);
    hipMemsetAsync(hf, 0, (size_t)RTOT * HH * sizeof(float), stream);
    hipMemsetAsync(BfA, 0, bf_bytes, stream);
    hipMemsetAsync(BfB, 0, bf_bytes, stream);

    conv_a<<<(MSUB * 16 * 512 / 8) / 256, 256, 0, stream>>>(P, Af);
    conv_w<<<16, 256, 0, stream>>>(Weg, 128, 8, WfGe);
    conv_w<<<16, 256, 0, stream>>>(Wdg, 128, 8, WfGd);
    conv_w<<<8,  256, 0, stream>>>(Weu, 64, 4, WfCe);
    conv_w<<<8,  256, 0, stream>>>(Wdu, 64, 4, WfCd);
    upd_x<<<RTOT / 256, 256, 0, stream>>>(x, 0, BfA);

    for (int t = 0; t < TT; ++t) {
        fused_gates<<<256, 256, 0, stream>>>(Af, BfA, BfB, WfGe, beg, hf, zf);
        fused_cand<<<256, 256, 0, stream>>>(Af, BfB, BfA, WfCe, beu, zf, hf,
                                            (t + 1 < TT) ? x : nullptr, t + 1,
                                            nullptr, nullptr, nullptr, 0, hor, 0);
    }
    for (int t = 0; t < hor; ++t) {
        fused_gates<<<256, 256, 0, stream>>>(Af, BfA, BfB, WfGd, bdg, hf, zf);
        fused_cand<<<256, 256, 0, stream>>>(Af, BfB, BfA, WfCd, bdu, zf, hf,
                                            nullptr, 0,
                                            Wp, bp, out, t, hor, 1);
    }
}

// Round 9
// 716.083 us; speedup vs baseline: 1.0892x; 1.0892x over previous
//
#include <hip/hip_runtime.h>
#include <hip/hip_bf16.h>
#include <math.h>

// Problem constants
#define BB 32
#define TT 12
#define NN 512
#define HH 64
#define DIN 65
#define MSUB 96        // ROWS/16 (ROWS = 3*512)
#define RTOT 16384     // BB*NN dense rows
#define PSUB 5         // 80 padded cols per batch
#define BUFSLOT 18432  // 36 subtiles x 512 f16 per staging buffer

typedef _Float16 f16;
typedef f16 f16x8 __attribute__((ext_vector_type(8)));
typedef float f32x4 __attribute__((ext_vector_type(4)));

#define GLD_LDS16(g, l) \
    __builtin_amdgcn_global_load_lds((const __attribute__((address_space(1))) void*)(g), \
                                     (__attribute__((address_space(3))) void*)(l), 16, 0, 0)

// Bf element address: node j (K-dim), batch b, local col p in [0,80)
__device__ __forceinline__ size_t bf_addr(int j, int b, int p) {
    return ((size_t)(((j >> 5) * 32 + b) * PSUB + (p >> 4)) * 64 + ((j >> 3) & 3) * 16 + (p & 15)) * 8 + (j & 7);
}

// ---------------- convert P (f32, 1536x512 row-major) -> fragment-major f16 A ----------------
__global__ __launch_bounds__(256) void conv_a(const float* __restrict__ P, f16* __restrict__ Af) {
    int u = blockIdx.x * 256 + threadIdx.x;  // 1536*512/8 slots
    int lane = u & 63;
    int su = u >> 6;
    int ks = su / MSUB, ms = su - ks * MSUB;
    int m = ms * 16 + (lane & 15);
    int k = ks * 32 + (lane >> 4) * 8;
    const float* src = &P[(size_t)m * 512 + k];
    f16x8 v;
#pragma unroll
    for (int i = 0; i < 8; ++i) v[i] = (f16)src[i];
    *(f16x8*)&Af[(size_t)u * 8] = v;
}

// -------- convert dense weight (195 x O f32) -> K-permuted fragment pack matching in-reg S^T --
__global__ __launch_bounds__(256) void conv_w(const float* __restrict__ W, int O, int OS,
                                              f16* __restrict__ Wf) {
    int u = blockIdx.x * 256 + threadIdx.x;
    if (u >= 8 * OS * 64) return;
    int lane = u & 63, slot = u >> 6;
    int s = slot / OS, os = slot - s * OS;
    int o = os * 16 + (lane & 15);
    int g = lane >> 4;
    f16x8 v;
#pragma unroll
    for (int i = 0; i < 8; ++i) {
        int f = 2 * s + (i >= 4 ? 1 : 0);
        int kl = f / 5, ps = f - kl * 5;
        int p = ps * 16 + 4 * g + (i & 3);
        v[i] = (f < 15 && p < 65) ? (f16)W[(size_t)(kl * 65 + p) * O + o] : (f16)0.f;
    }
    *(f16x8*)&Wf[(size_t)u * 8] = v;
}

// ---------------- write x[b,t,:,0] into Bf p=0 col (prologue) ----------------
__global__ __launch_bounds__(256) void upd_x(const float* __restrict__ x, int t,
                                             f16* __restrict__ Bf) {
    int idx = blockIdx.x * 256 + threadIdx.x;
    if (idx >= RTOT) return;
    int b = idx >> 9, n = idx & 511;
    Bf[bf_addr(n, b, 0)] = (f16)x[((size_t)b * TT + t) * NN + n];
}

// ---- staging: 36 slots (24 A, 10 B, 2 dup-pad), wave-contiguous 9/wave for uniform vmcnt ----
__device__ __forceinline__ void stage3(const f16* __restrict__ Af,
                                       const f16* __restrict__ BfIn,
                                       f16* __restrict__ lds,
                                       int b, int mb, int wave, int lane, int buf, int it) {
#pragma unroll
    for (int i = 0; i < 9; ++i) {
        int q = wave * 9 + i;
        int qq = (q >= 34) ? (q - 10) : q;  // dup pads re-load B slots 24,25
        const f16* src;
        if (qq < 24) {
            int ksl = qq / 12, aid = qq % 12;
            int msub = (aid >> 2) * 32 + mb * 4 + (aid & 3);
            src = &Af[((size_t)((it * 2 + ksl) * MSUB + msub) * 64 + lane) * 8];
        } else {
            int qb = qq - 24;
            int ksl = qb / 5, ps = qb - ksl * 5;
            src = &BfIn[((size_t)(((it * 2 + ksl) * 32 + b) * PSUB + ps) * 64 + lane) * 8];
        }
        GLD_LDS16(src, &lds[buf * BUFSLOT + q * 512 + lane * 8]);
    }
}

// ---------------- mm: S^T chunk for (batch b, node-band mb) into acc[15] ----------------
// 3-buffer pipeline, raw s_barrier + counted vmcnt(9): one stage-batch stays in flight
// across each barrier (T3/T4). stage(it+2) AFTER barrier(it) => buffer reuse race-free.
__device__ __forceinline__ void gcn_mm(const f16* __restrict__ Af,
                                       const f16* __restrict__ BfIn,
                                       f16* __restrict__ lds,
                                       int b, int mb, int wave, int lane,
                                       f32x4 (&acc)[15]) {
    stage3(Af, BfIn, lds, b, mb, wave, lane, 0, 0);
    stage3(Af, BfIn, lds, b, mb, wave, lane, 1, 1);
#pragma unroll
    for (int it = 0; it < 8; ++it) {
        if (it < 7) {
            asm volatile("s_waitcnt vmcnt(9)" ::: "memory");
        } else {
            asm volatile("s_waitcnt vmcnt(0)" ::: "memory");
        }
        __builtin_amdgcn_sched_barrier(0);
        __builtin_amdgcn_s_barrier();
        __builtin_amdgcn_sched_barrier(0);
        if (it + 2 < 8) stage3(Af, BfIn, lds, b, mb, wave, lane, (it + 2) % 3, it + 2);
        const f16* L = &lds[(it % 3) * BUFSLOT];
#pragma unroll
        for (int s = 0; s < 2; ++s) {
            f16x8 bfr[5], afr[3];
#pragma unroll
            for (int ps = 0; ps < PSUB; ++ps)
                bfr[ps] = *(const f16x8*)&L[(24 + s * 5 + ps) * 512 + lane * 8];
#pragma unroll
            for (int k = 0; k < 3; ++k)
                afr[k] = *(const f16x8*)&L[(s * 12 + k * 4 + wave) * 512 + lane * 8];
            __builtin_amdgcn_s_setprio(1);
#pragma unroll
            for (int k = 0; k < 3; ++k)
#pragma unroll
                for (int ps = 0; ps < PSUB; ++ps)
                    acc[k * 5 + ps] = __builtin_amdgcn_mfma_f32_16x16x32_f16(bfr[ps], afr[k], acc[k * 5 + ps], 0, 0, 0);
            __builtin_amdgcn_s_setprio(0);
        }
    }
}

// build dense A-operand fragments from acc (K-permuted to match conv_w)
__device__ __forceinline__ void build_ad(const f32x4 (&acc)[15], f16x8 (&ad)[8]) {
#pragma unroll
    for (int s = 0; s < 8; ++s)
#pragma unroll
        for (int i = 0; i < 4; ++i) {
            ad[s][i] = (f16)acc[2 * s][i];
            ad[s][4 + i] = (s < 7) ? (f16)acc[2 * s + 1][i] : (f16)0.f;
        }
}

// ---------------- fused gates phase: mm + zr-dense + sigmoid; z->zf, r*h->BfOut; p0 copy ------
__global__ __launch_bounds__(256, 1) void fused_gates(const f16* __restrict__ Af,
                                                      const f16* __restrict__ BfIn,
                                                      f16* __restrict__ BfOut,
                                                      const f16* __restrict__ Wf,
                                                      const float* __restrict__ bias,
                                                      const float* __restrict__ hf,
                                                      float* __restrict__ zf) {
    __shared__ f16 lds[3 * BUFSLOT];
    int tid = threadIdx.x, wave = tid >> 6, lane = tid & 63;
    int b = blockIdx.x >> 3, mb = blockIdx.x & 7;
    f32x4 acc[15] = {};
    gcn_mm(Af, BfIn, lds, b, mb, wave, lane, acc);

    f16x8 ad[8];
    build_ad(acc, ad);

    __syncthreads();  // full drain; safe to reuse lds for W
#pragma unroll
    for (int qi = 0; qi < 16; ++qi) {
        int q = qi * 4 + wave;  // 64 W subtiles
        GLD_LDS16(&Wf[((size_t)q * 64 + lane) * 8], &lds[q * 512 + lane * 8]);
    }
    __syncthreads();

    f32x4 acc2[8] = {};
#pragma unroll
    for (int s = 0; s < 8; ++s)
#pragma unroll
        for (int os = 0; os < 8; ++os) {
            f16x8 w = *(const f16x8*)&lds[(s * 8 + os) * 512 + lane * 8];
            acc2[os] = __builtin_amdgcn_mfma_f32_16x16x32_f16(ad[s], w, acc2[os], 0, 0, 0);
        }

    int o_l = lane & 15, g = lane >> 4;
    int node0 = mb * 64 + wave * 16;
    int rf = b * 32 + mb * 4 + wave;
#pragma unroll
    for (int os = 0; os < 4; ++os) {  // z
        f32x4 v;
#pragma unroll
        for (int rI = 0; rI < 4; ++rI)
            v[rI] = 1.f / (1.f + expf(-(acc2[os][rI] + bias[os * 16 + o_l])));
        *(f32x4*)&zf[((size_t)(rf * 4 + os) * 64 + lane) * 4] = v;
    }
#pragma unroll
    for (int os = 4; os < 8; ++os) {  // r -> r*h
        int osh = os - 4;
        f32x4 hv = *(const f32x4*)&hf[((size_t)(rf * 4 + osh) * 64 + lane) * 4];
#pragma unroll
        for (int rI = 0; rI < 4; ++rI) {
            float rr = 1.f / (1.f + expf(-(acc2[os][rI] + bias[64 + osh * 16 + o_l])));
            int n = node0 + 4 * g + rI;
            BfOut[bf_addr(n, b, 1 + osh * 16 + o_l)] = (f16)(rr * hv[rI]);
        }
    }
    if (tid < 64) {  // p0 col copy (x or go)
        int n = mb * 64 + tid;
        BfOut[bf_addr(n, b, 0)] = BfIn[bf_addr(n, b, 0)];
    }
}

// -------- fused cand phase: mm + cand-dense + tanh + GRU update; h->hf,BfOut; tail x/proj -----
__global__ __launch_bounds__(256, 1) void fused_cand(const f16* __restrict__ Af,
                                                     const f16* __restrict__ BfIn,
                                                     f16* __restrict__ BfOut,
                                                     const f16* __restrict__ Wf,
                                                     const float* __restrict__ bias,
                                                     const float* __restrict__ zf,
                                                     float* __restrict__ hf,
                                                     const float* __restrict__ xnext, int tnext,
                                                     const float* __restrict__ Wp,
                                                     const float* __restrict__ bp,
                                                     float* __restrict__ outp, int t, int hor,
                                                     int mode) {
    __shared__ f16 lds[3 * BUFSLOT];
    int tid = threadIdx.x, wave = tid >> 6, lane = tid & 63;
    int b = blockIdx.x >> 3, mb = blockIdx.x & 7;
    f32x4 acc[15] = {};
    gcn_mm(Af, BfIn, lds, b, mb, wave, lane, acc);

    f16x8 ad[8];
    build_ad(acc, ad);

    __syncthreads();
#pragma unroll
    for (int qi = 0; qi < 8; ++qi) {
        int q = qi * 4 + wave;  // 32 W subtiles
        GLD_LDS16(&Wf[((size_t)q * 64 + lane) * 8], &lds[q * 512 + lane * 8]);
    }
    __syncthreads();

    f32x4 acc2[4] = {};
#pragma unroll
    for (int s = 0; s < 8; ++s)
#pragma unroll
        for (int os = 0; os < 4; ++os) {
            f16x8 w = *(const f16x8*)&lds[(s * 4 + os) * 512 + lane * 8];
            acc2[os] = __builtin_amdgcn_mfma_f32_16x16x32_f16(ad[s], w, acc2[os], 0, 0, 0);
        }

    int o_l = lane & 15, g = lane >> 4;
    int node0 = mb * 64 + wave * 16;
    int rf = b * 32 + mb * 4 + wave;
    float pp[4] = {0.f, 0.f, 0.f, 0.f};
#pragma unroll
    for (int os = 0; os < 4; ++os) {
        int o = os * 16 + o_l;
        float wp = mode ? Wp[o] : 0.f;
        f32x4 zv = *(const f32x4*)&zf[((size_t)(rf * 4 + os) * 64 + lane) * 4];
        f32x4 hv = *(const f32x4*)&hf[((size_t)(rf * 4 + os) * 64 + lane) * 4];
        f32x4 hn;
#pragma unroll
        for (int rI = 0; rI < 4; ++rI) {
            float hc = tanhf(acc2[os][rI] + bias[o]);
            hn[rI] = (1.f - zv[rI]) * hv[rI] + zv[rI] * hc;
            pp[rI] += hn[rI] * wp;
        }
        *(f32x4*)&hf[((size_t)(rf * 4 + os) * 64 + lane) * 4] = hn;
#pragma unroll
        for (int rI = 0; rI < 4; ++rI) {
            int n = node0 + 4 * g + rI;
            BfOut[bf_addr(n, b, 1 + o)] = (f16)hn[rI];
        }
    }
    if (mode) {  // decoder: proj + out + p0
#pragma unroll
        for (int m = 1; m < 16; m <<= 1)
#pragma unroll
            for (int rI = 0; rI < 4; ++rI) pp[rI] += __shfl_xor(pp[rI], m, 64);
        if (o_l == 0) {
#pragma unroll
            for (int rI = 0; rI < 4; ++rI) {
                int n = node0 + 4 * g + rI;
                float v = pp[rI] + bp[0];
                outp[((size_t)b * hor + t) * NN + n] = v;
                BfOut[bf_addr(n, b, 0)] = (f16)v;
            }
        }
    } else {  // encoder: next x (or 0 at seam)
        if (o_l == 0) {
#pragma unroll
            for (int rI = 0; rI < 4; ++rI) {
                int n = node0 + 4 * g + rI;
                float v = xnext ? xnext[((size_t)b * TT + tnext) * NN + n] : 0.f;
                BfOut[bf_addr(n, b, 0)] = (f16)v;
            }
        }
    }
}

extern "C" void kernel_launch(void* const* d_in, const int* in_sizes, int n_in,
                              void* d_out, int out_size, void* d_ws, size_t ws_size,
                              hipStream_t stream) {
    const float* x   = (const float*)d_in[0];
    const float* P   = (const float*)d_in[1];
    const float* Weg = (const float*)d_in[2];
    const float* beg = (const float*)d_in[3];
    const float* Weu = (const float*)d_in[4];
    const float* beu = (const float*)d_in[5];
    const float* Wdg = (const float*)d_in[6];
    const float* bdg = (const float*)d_in[7];
    const float* Wdu = (const float*)d_in[8];
    const float* bdu = (const float*)d_in[9];
    const float* Wp  = (const float*)d_in[10];
    const float* bp  = (const float*)d_in[11];
    float* out = (float*)d_out;
    int hor = out_size / (BB * NN);

    float* ws = (float*)d_ws;
    size_t off = 0;
    float* hf = ws + off; off += (size_t)RTOT * HH;                    // 4 MB
    float* zf = ws + off; off += (size_t)RTOT * HH;                    // 4 MB
    f16* BfA  = (f16*)(ws + off); off += 16 * 32 * PSUB * 64 * 8 / 2;  // 2.62 MB
    f16* BfB  = (f16*)(ws + off); off += 16 * 32 * PSUB * 64 * 8 / 2;
    f16* Af   = (f16*)(ws + off); off += (size_t)MSUB * 16 * 512 / 2;
    f16* WfGe = (f16*)(ws + off); off += 8 * 8 * 64 * 8 / 2;
    f16* WfGd = (f16*)(ws + off); off += 8 * 8 * 64 * 8 / 2;
    f16* WfCe = (f16*)(ws + off); off += 8 * 4 * 64 * 8 / 2;
    f16* WfCd = (f16*)(ws + off); off += 8 * 4 * 64 * 8 / 2;

    size_t bf_bytes = (size_t)16 * 32 * PSUB * 64 * 8 * sizeof(f16);
    hipMemsetAsync(hf, 0, (size_t)RTOT * HH * sizeof(float), stream);
    hipMemsetAsync(BfA, 0, bf_bytes, stream);
    hipMemsetAsync(BfB, 0, bf_bytes, stream);

    conv_a<<<(MSUB * 16 * 512 / 8) / 256, 256, 0, stream>>>(P, Af);
    conv_w<<<16, 256, 0, stream>>>(Weg, 128, 8, WfGe);
    conv_w<<<16, 256, 0, stream>>>(Wdg, 128, 8, WfGd);
    conv_w<<<8,  256, 0, stream>>>(Weu, 64, 4, WfCe);
    conv_w<<<8,  256, 0, stream>>>(Wdu, 64, 4, WfCd);
    upd_x<<<RTOT / 256, 256, 0, stream>>>(x, 0, BfA);

    for (int t = 0; t < TT; ++t) {
        fused_gates<<<256, 256, 0, stream>>>(Af, BfA, BfB, WfGe, beg, hf, zf);
        fused_cand<<<256, 256, 0, stream>>>(Af, BfB, BfA, WfCe, beu, zf, hf,
                                            (t + 1 < TT) ? x : nullptr, t + 1,
                                            nullptr, nullptr, nullptr, 0, hor, 0);
    }
    for (int t = 0; t < hor; ++t) {
        fused_gates<<<256, 256, 0, stream>>>(Af, BfA, BfB, WfGd, bdg, hf, zf);
        fused_cand<<<256, 256, 0, stream>>>(Af, BfB, BfA, WfCd, bdu, zf, hf,
                                            nullptr, 0,
                                            Wp, bp, out, t, hor, 1);
    }
}